// Round 5
// baseline (353.619 us; speedup 1.0000x reference)
//
#include <hip/hip_runtime.h>
#include <hip/hip_bf16.h>

typedef __bf16 bf16;
typedef __bf16 bf16x4 __attribute__((ext_vector_type(4)));
typedef __bf16 bf16x8 __attribute__((ext_vector_type(8)));
typedef float f32x4 __attribute__((ext_vector_type(4)));

#define N_NODES 131072
#define CH      512
#define HD      128
#define LMAX    8192
#define NG      16

typedef __attribute__((address_space(3))) unsigned int lds_u32;
typedef __attribute__((address_space(1))) const unsigned int g_u32;

__device__ __forceinline__ void gload16(const void* gp, void* lp) {
    __builtin_amdgcn_global_load_lds((g_u32*)gp, (lds_u32*)lp, 16, 0, 0);
}

// ---------------- K0: W (3x128x512 fp32) -> bf16, staging-order, inverse-XOR-swizzled ----
// wsW granule layout: [c=16][j=384][g=4] of 8 elems; value = W3[j][c*32 + ((g ^ ((j>>1)&3))<<3) + e]
// K1 reads granule g = lh ^ ((j>>1)&3) to get cols lh*8..lh*8+7 (conflict-free: 2 lanes/bank).
__global__ __launch_bounds__(256, 1) void k0_prep(
    const float* __restrict__ Wq, const float* __restrict__ Wk,
    const float* __restrict__ Wv, bf16* __restrict__ wsW)
{
    int t = blockIdx.x * 256 + threadIdx.x;      // 24576 granules of 8 elements
    int c = t / 1536;                            // K-chunk (BK=32)
    int r = t % 1536;
    int j = r >> 2, g = r & 3;
    const float* Wrow = (j < 128) ? (Wq + (size_t)j * CH)
                       : (j < 256) ? (Wk + (size_t)(j - 128) * CH)
                                   : (Wv + (size_t)(j - 256) * CH);
    int col0 = c * 32 + ((g ^ ((j >> 1) & 3)) << 3);
    float4 f0 = *(const float4*)(Wrow + col0);
    float4 f1 = *(const float4*)(Wrow + col0 + 4);
    bf16x8 o;
    o[0] = (bf16)f0.x; o[1] = (bf16)f0.y; o[2] = (bf16)f0.z; o[3] = (bf16)f0.w;
    o[4] = (bf16)f1.x; o[5] = (bf16)f1.y; o[6] = (bf16)f1.z; o[7] = (bf16)f1.w;
    *(bf16x8*)(wsW + (size_t)t * 8) = o;
}

// ---------------- K1: QKV projection, bf16 MFMA, BK=32, 2 blocks/CU ----------------
// grid 1024 x 512 threads; tile 128 nodes x 384 cols; 70 KB LDS; dbuf, loads issued pre-compute.
__global__ __launch_bounds__(512, 4) void k1_proj(
    const float* __restrict__ x, const bf16* __restrict__ wsW,
    bf16* __restrict__ qo, bf16* __restrict__ ko, bf16* __restrict__ vo,
    float* __restrict__ sumsq)
{
    __shared__ bf16 As[2][128][40];   // 20,480 B (pad 8: rows 80 B, frag reads spread banks)
    __shared__ bf16 Bs[2][12288];     // 49,152 B (linear [384][32], swizzled content)
    __shared__ float rq[8], rk[8];

    const int tid = threadIdx.x;
    const int lane = tid & 63;
    const int w = tid >> 6;
    const int wr = w >> 2, wc = w & 3;          // 2x4 wave grid
    const int lr = lane & 15, lh = lane >> 4;
    const int n0 = blockIdx.x * 128;
    const int ar = tid >> 2, ac = tid & 3;      // A-staging: row ar, col-octet ac

    f32x4 acc[4][6];
    #pragma unroll
    for (int mi = 0; mi < 4; mi++)
        #pragma unroll
        for (int ni = 0; ni < 6; ni++)
            acc[mi][ni] = (f32x4){0.f, 0.f, 0.f, 0.f};

    float4 areg0, areg1;

    // prologue: stage chunk 0
    {
        const char* wb = (const char*)wsW + w * 1024 + lane * 16;
        char* db = (char*)(&Bs[0][0]) + w * 1024;
        #pragma unroll
        for (int i = 0; i < 3; i++) gload16(wb + i * 8192, db + i * 8192);
        areg0 = *(const float4*)(x + (size_t)(n0 + ar) * CH + ac * 8);
        areg1 = *(const float4*)(x + (size_t)(n0 + ar) * CH + ac * 8 + 4);
        bf16x8 t;
        t[0] = (bf16)areg0.x; t[1] = (bf16)areg0.y; t[2] = (bf16)areg0.z; t[3] = (bf16)areg0.w;
        t[4] = (bf16)areg1.x; t[5] = (bf16)areg1.y; t[6] = (bf16)areg1.z; t[7] = (bf16)areg1.w;
        *(bf16x8*)&As[0][ar][ac * 8] = t;
        __syncthreads();
    }

    for (int c = 0; c < 16; c++) {
        const int cur = c & 1, nxt = cur ^ 1;
        if (c < 15) {
            const char* wb = (const char*)wsW + (size_t)(c + 1) * 24576 + w * 1024 + lane * 16;
            char* db = (char*)(&Bs[nxt][0]) + w * 1024;
            #pragma unroll
            for (int i = 0; i < 3; i++) gload16(wb + i * 8192, db + i * 8192);
            areg0 = *(const float4*)(x + (size_t)(n0 + ar) * CH + (c + 1) * 32 + ac * 8);
            areg1 = *(const float4*)(x + (size_t)(n0 + ar) * CH + (c + 1) * 32 + ac * 8 + 4);
        }
        bf16x8 af[4];
        #pragma unroll
        for (int mi = 0; mi < 4; mi++)
            af[mi] = *(const bf16x8*)&As[cur][wr * 64 + mi * 16 + lr][lh * 8];
        #pragma unroll
        for (int mi = 0; mi < 4; mi++) {
            #pragma unroll
            for (int ni = 0; ni < 6; ni++) {
                int j = wc * 96 + ni * 16 + lr;
                int g = lh ^ ((j >> 1) & 3);
                bf16x8 bf_ = *(const bf16x8*)&Bs[cur][j * 32 + (g << 3)];
                acc[mi][ni] = __builtin_amdgcn_mfma_f32_16x16x32_bf16(
                    af[mi], bf_, acc[mi][ni], 0, 0, 0);
            }
        }
        if (c < 15) {
            bf16x8 t;
            t[0] = (bf16)areg0.x; t[1] = (bf16)areg0.y; t[2] = (bf16)areg0.z; t[3] = (bf16)areg0.w;
            t[4] = (bf16)areg1.x; t[5] = (bf16)areg1.y; t[6] = (bf16)areg1.z; t[7] = (bf16)areg1.w;
            *(bf16x8*)&As[nxt][ar][ac * 8] = t;
        }
        __syncthreads();
    }

    // epilogue: write bf16 q/k/v + sum of squares (fp32, pre-quantization)
    float sq = 0.f, sk = 0.f;
    #pragma unroll
    for (int mi = 0; mi < 4; mi++) {
        #pragma unroll
        for (int ni = 0; ni < 6; ni++) {
            int col = wc * 96 + ni * 16 + lr;
            int arr = col >> 7, cc = col & 127;
            bf16* dst = (arr == 0) ? qo : (arr == 1) ? ko : vo;
            #pragma unroll
            for (int r = 0; r < 4; r++) {
                int row = n0 + wr * 64 + mi * 16 + lh * 4 + r;
                float val = acc[mi][ni][r];
                dst[(size_t)row * HD + cc] = (bf16)val;
                if (arr == 0) sq += val * val;
                else if (arr == 1) sk += val * val;
            }
        }
    }
    #pragma unroll
    for (int off = 32; off > 0; off >>= 1) {
        sq += __shfl_down(sq, off);
        sk += __shfl_down(sk, off);
    }
    if (lane == 0) { rq[w] = sq; rk[w] = sk; }
    __syncthreads();
    if (tid == 0) {
        float a = 0.f, b = 0.f;
        #pragma unroll
        for (int i = 0; i < 8; i++) { a += rq[i]; b += rk[i]; }
        atomicAdd(&sumsq[0], a);
        atomicAdd(&sumsq[1], b);
    }
}

// ---------------- K2: per-graph k^T v via MFMA (node-dim as K) ----------------
// grid 256 blocks (16 graphs x 16 chunks of 512 rows) x 512 threads (8 waves, 2x4).
__global__ __launch_bounds__(512, 1) void k2_kv(
    const bf16* __restrict__ ko, const bf16* __restrict__ vo,
    float* __restrict__ part_kv, float* __restrict__ part_ks)
{
    __shared__ __align__(16) char smem[16640];   // kt[32][130] | vt[32][130]; reused as f32 scr
    bf16 (*kt)[130] = (bf16(*)[130])smem;
    bf16 (*vt)[130] = (bf16(*)[130])(smem + 8320);
    float* scr = (float*)smem;

    const int tid = threadIdx.x, lane = tid & 63, w = tid >> 6;
    const int wr = w >> 2, wc = w & 3;           // 2 m-groups x 4 d-groups
    const int lr = lane & 15, lh = lane >> 4;
    const int b = blockIdx.x >> 4, cch = blockIdx.x & 15;
    const size_t l0 = (size_t)b * LMAX + (size_t)cch * 512;
    const int sr = tid >> 4, sc = tid & 15;      // staging row / col8

    f32x4 acc[4][2];
    #pragma unroll
    for (int mi = 0; mi < 4; mi++)
        #pragma unroll
        for (int ni = 0; ni < 2; ni++)
            acc[mi][ni] = (f32x4){0.f, 0.f, 0.f, 0.f};
    float ks8[8] = {};

    uint4 kk4 = *(const uint4*)&ko[(l0 + sr) * HD + sc * 8];
    uint4 vv4 = *(const uint4*)&vo[(l0 + sr) * HD + sc * 8];

    for (int lt = 0; lt < 512; lt += 32) {
        __syncthreads();   // prev compute done
        #pragma unroll
        for (int j2 = 0; j2 < 4; j2++) {
            *(unsigned int*)&kt[sr][sc * 8 + j2 * 2] = ((const unsigned int*)&kk4)[j2];
            *(unsigned int*)&vt[sr][sc * 8 + j2 * 2] = ((const unsigned int*)&vv4)[j2];
        }
        #pragma unroll
        for (int j = 0; j < 8; j++) ks8[j] += (float)((const bf16*)&kk4)[j];
        __syncthreads();   // tiles published
        if (lt + 32 < 512) {   // prefetch next tile during compute
            kk4 = *(const uint4*)&ko[(l0 + lt + 32 + sr) * HD + sc * 8];
            vv4 = *(const uint4*)&vo[(l0 + lt + 32 + sr) * HD + sc * 8];
        }
        bf16x8 a[4], bb[2];
        #pragma unroll
        for (int mi = 0; mi < 4; mi++) {
            int m = wr * 64 + mi * 16 + lr;
            #pragma unroll
            for (int j = 0; j < 8; j++) a[mi][j] = kt[lh * 8 + j][m];
        }
        #pragma unroll
        for (int ni = 0; ni < 2; ni++) {
            int d = wc * 32 + ni * 16 + lr;
            #pragma unroll
            for (int j = 0; j < 8; j++) bb[ni][j] = vt[lh * 8 + j][d];
        }
        #pragma unroll
        for (int mi = 0; mi < 4; mi++)
            #pragma unroll
            for (int ni = 0; ni < 2; ni++)
                acc[mi][ni] = __builtin_amdgcn_mfma_f32_16x16x32_bf16(
                    a[mi], bb[ni], acc[mi][ni], 0, 0, 0);
    }

    // ks partial: reduce per-thread col-sums across the 32 row-groups
    __syncthreads();
    #pragma unroll
    for (int j = 0; j < 8; j++) scr[tid * 8 + j] = ks8[j];
    __syncthreads();
    if (tid < 128) {
        float s = 0.f;
        #pragma unroll
        for (int g = 0; g < 32; g++)
            s += scr[((g << 4) | (tid >> 3)) * 8 + (tid & 7)];
        part_ks[blockIdx.x * HD + tid] = s;
    }

    float* dst = part_kv + (size_t)blockIdx.x * 16384;
    #pragma unroll
    for (int mi = 0; mi < 4; mi++)
        #pragma unroll
        for (int ni = 0; ni < 2; ni++)
            #pragma unroll
            for (int r = 0; r < 4; r++) {
                int m = wr * 64 + mi * 16 + lh * 4 + r;
                int d = wc * 32 + ni * 16 + lr;
                dst[m * HD + d] = acc[mi][ni][r];
            }
}

// ---------------- K2b: reduce 16 partials/graph, apply s_q*s_k, write kvs^T ----------------
__global__ __launch_bounds__(256, 1) void k2b_reduce(
    const float* __restrict__ part_kv, const float* __restrict__ part_ks,
    const float* __restrict__ sumsq,
    bf16* __restrict__ kvsT, float* __restrict__ ks_sum_s)
{
    const int b = blockIdx.x >> 3, ms = blockIdx.x & 7, tid = threadIdx.x;
    const float s_qk = rsqrtf(sumsq[0]) * rsqrtf(sumsq[1]);

    #pragma unroll
    for (int i = 0; i < 8; i++) {
        int idx = i * 256 + tid;               // 2048 outputs for this m-slice
        int m = ms * 16 + (idx >> 7), d = idx & 127;
        float s = 0.f;
        #pragma unroll
        for (int c = 0; c < 16; c++)
            s += part_kv[((size_t)(b * 16 + c) << 14) + (m << 7) + d];
        kvsT[((size_t)b << 14) + (d << 7) + m] = (bf16)(s * s_qk);
    }
    if (ms == 0 && tid < 128) {
        float s = 0.f;
        #pragma unroll
        for (int c = 0; c < 16; c++)
            s += part_ks[(b * 16 + c) * HD + tid];
        ks_sum_s[b * HD + tid] = s * s_qk;
    }
}

// ---------------- K3: out = (q @ kvsT + 16 v) / (q . ks_sum_s + 16) ----------------
// 70 KB LDS -> 2 blocks/CU; kvsT B-frags read direct from global (L2-hot, 32 KB/graph).
__global__ __launch_bounds__(256, 2) void k3_out(
    const bf16* __restrict__ qo, const bf16* __restrict__ vo,
    const bf16* __restrict__ kvsT, const float* __restrict__ ks_sum_s,
    float* __restrict__ out)
{
    __shared__ bf16 qs[128][136];
    __shared__ bf16 vsh[128][136];
    __shared__ float kss[128];
    __shared__ float denom[128];
    const int tid = threadIdx.x, lane = tid & 63, w = tid >> 6;
    const int lr = lane & 15, lh = lane >> 4;
    const int n0 = blockIdx.x * 128;
    const int b = n0 >> 13;

    #pragma unroll
    for (int i = 0; i < 8; i++) {
        int idx = tid + i * 256;
        int r = idx >> 4, c8 = idx & 15;
        *(bf16x8*)&qs[r][c8 * 8]  = *(const bf16x8*)&qo[(size_t)(n0 + r) * HD + c8 * 8];
        *(bf16x8*)&vsh[r][c8 * 8] = *(const bf16x8*)&vo[(size_t)(n0 + r) * HD + c8 * 8];
    }
    if (tid < 128) kss[tid] = ks_sum_s[b * HD + tid];
    __syncthreads();

    if (tid < 128) {
        float s = 0.f;
        #pragma unroll 8
        for (int m = 0; m < HD; m++) s += (float)qs[tid][m] * kss[m];
        denom[tid] = s + 16.0f;
    }

    f32x4 acc[2][8];
    #pragma unroll
    for (int mi = 0; mi < 2; mi++)
        #pragma unroll
        for (int ni = 0; ni < 8; ni++)
            acc[mi][ni] = (f32x4){0.f, 0.f, 0.f, 0.f};

    #pragma unroll
    for (int k0 = 0; k0 < HD; k0 += 32) {
        bf16x8 a[2], bb[8];
        #pragma unroll
        for (int mi = 0; mi < 2; mi++)
            a[mi] = *(const bf16x8*)&qs[w * 32 + mi * 16 + lr][k0 + lh * 8];
        #pragma unroll
        for (int ni = 0; ni < 8; ni++)
            bb[ni] = *(const bf16x8*)&kvsT[(size_t)b * 16384 + (size_t)(ni * 16 + lr) * HD + k0 + lh * 8];
        #pragma unroll
        for (int mi = 0; mi < 2; mi++)
            #pragma unroll
            for (int ni = 0; ni < 8; ni++)
                acc[mi][ni] = __builtin_amdgcn_mfma_f32_16x16x32_bf16(
                    a[mi], bb[ni], acc[mi][ni], 0, 0, 0);
    }
    __syncthreads();   // denom ready

    #pragma unroll
    for (int mi = 0; mi < 2; mi++) {
        #pragma unroll
        for (int ni = 0; ni < 8; ni++) {
            int col = ni * 16 + lr;
            #pragma unroll
            for (int r = 0; r < 4; r++) {
                int row = w * 32 + mi * 16 + lh * 4 + r;
                float vv = (float)vsh[row][col];
                out[(size_t)(n0 + row) * HD + col] =
                    (acc[mi][ni][r] + 16.0f * vv) / denom[row];
            }
        }
    }
}

// ---------------- launch ----------------
extern "C" void kernel_launch(void* const* d_in, const int* in_sizes, int n_in,
                              void* d_out, int out_size, void* d_ws, size_t ws_size,
                              hipStream_t stream)
{
    const float* x  = (const float*)d_in[0];
    const float* Wq = (const float*)d_in[1];
    const float* Wk = (const float*)d_in[2];
    const float* Wv = (const float*)d_in[3];

    char* ws = (char*)d_ws;
    const size_t Q_OFF   = 0;                       // 131072*128*2 = 33554432
    const size_t K_OFF   = 33554432;
    const size_t V_OFF   = 67108864;
    const size_t PKV_OFF = 100663296;               // 256*16384*4 = 16777216
    const size_t PKS_OFF = 117440512;               // 256*128*4   = 131072
    const size_t KVS_OFF = 117571584;               // 16*16384*2  = 524288
    const size_t KSS_OFF = 118095872;               // 16*128*4    = 8192
    const size_t SSQ_OFF = 118104064;               // 2*4
    const size_t NEED    = 118104072;
    if (ws_size < NEED) return;

    bf16*  qo      = (bf16*)(ws + Q_OFF);
    bf16*  ko      = (bf16*)(ws + K_OFF);
    bf16*  vo      = (bf16*)(ws + V_OFF);
    float* part_kv = (float*)(ws + PKV_OFF);
    float* part_ks = (float*)(ws + PKS_OFF);
    bf16*  kvsT    = (bf16*)(ws + KVS_OFF);
    float* ks_sum  = (float*)(ws + KSS_OFF);
    float* sumsq   = (float*)(ws + SSQ_OFF);
    // wsW (393216 B) overlaps part_kv region: live only k0->k1, dead before k2 writes part_kv
    bf16*  wsW     = (bf16*)(ws + PKV_OFF);

    hipMemsetAsync(sumsq, 0, 8, stream);
    k0_prep<<<dim3(96), dim3(256), 0, stream>>>(Wq, Wk, Wv, wsW);
    k1_proj<<<dim3(N_NODES / 128), dim3(512), 0, stream>>>(x, wsW, qo, ko, vo, sumsq);
    k2_kv<<<dim3(256), dim3(512), 0, stream>>>(ko, vo, part_kv, part_ks);
    k2b_reduce<<<dim3(128), dim3(256), 0, stream>>>(part_kv, part_ks, sumsq, kvsT, ks_sum);
    k3_out<<<dim3(N_NODES / 128), dim3(256), 0, stream>>>(qo, vo, kvsT, ks_sum, (float*)d_out);
}

// Round 7
// 254.878 us; speedup vs baseline: 1.3874x; 1.3874x over previous
//
#include <hip/hip_runtime.h>
#include <hip/hip_bf16.h>

typedef __bf16 bf16;
typedef __bf16 bf16x4 __attribute__((ext_vector_type(4)));
typedef __bf16 bf16x8 __attribute__((ext_vector_type(8)));
typedef float f32x4 __attribute__((ext_vector_type(4)));

#define N_NODES 131072
#define CH      512
#define HD      128
#define LMAX    8192
#define NG      16

typedef __attribute__((address_space(3))) unsigned int lds_u32;
typedef __attribute__((address_space(1))) const unsigned int g_u32;

__device__ __forceinline__ void gload16(const void* gp, void* lp) {
    __builtin_amdgcn_global_load_lds((g_u32*)gp, (lds_u32*)lp, 16, 0, 0);
}

// ---------------- K0: W (3x128x512 fp32) -> bf16, staging-order, inverse-XOR-swizzled ----
// wsW granule layout: [c=16][j=384][g=4] of 8 elems; value = W3[j][c*32 + ((g ^ ((j>>1)&3))<<3) + e]
// K1 reads granule g = lh ^ ((j>>1)&3) to get cols lh*8..lh*8+7.
__global__ __launch_bounds__(256, 1) void k0_prep(
    const float* __restrict__ Wq, const float* __restrict__ Wk,
    const float* __restrict__ Wv, bf16* __restrict__ wsW)
{
    int t = blockIdx.x * 256 + threadIdx.x;      // 24576 granules of 8 elements
    int c = t / 1536;                            // K-chunk (BK=32)
    int r = t % 1536;
    int j = r >> 2, g = r & 3;
    const float* Wrow = (j < 128) ? (Wq + (size_t)j * CH)
                       : (j < 256) ? (Wk + (size_t)(j - 128) * CH)
                                   : (Wv + (size_t)(j - 256) * CH);
    int col0 = c * 32 + ((g ^ ((j >> 1) & 3)) << 3);
    float4 f0 = *(const float4*)(Wrow + col0);
    float4 f1 = *(const float4*)(Wrow + col0 + 4);
    bf16x8 o;
    o[0] = (bf16)f0.x; o[1] = (bf16)f0.y; o[2] = (bf16)f0.z; o[3] = (bf16)f0.w;
    o[4] = (bf16)f1.x; o[5] = (bf16)f1.y; o[6] = (bf16)f1.z; o[7] = (bf16)f1.w;
    *(bf16x8*)(wsW + (size_t)t * 8) = o;
}

// ---------------- K1: QKV projection, bf16 MFMA, 64x384 tile, BK=32, 2 blocks/CU ----------------
// grid 2048 x 512 threads; acc 48 f32/thread -> ~95 VGPR, fits the 128-VGPR cap of
// __launch_bounds__(512,2) (2nd arg behaves as min BLOCKS/CU here -- 4 forced 64 VGPR, spilled).
__global__ __launch_bounds__(512, 2) void k1_proj(
    const float* __restrict__ x, const bf16* __restrict__ wsW,
    bf16* __restrict__ qo, bf16* __restrict__ ko, bf16* __restrict__ vo,
    float* __restrict__ sumsq)
{
    __shared__ bf16 As[2][64][40];    // 10,240 B (pad 8)
    __shared__ bf16 Bs[2][12288];     // 49,152 B (linear [384][32], swizzled content)
    __shared__ float rq[8], rk[8];

    const int tid = threadIdx.x;
    const int lane = tid & 63;
    const int w = tid >> 6;                     // 8 waves: wave w -> cols w*48..w*48+47
    const int lr = lane & 15, lh = lane >> 4;
    const int n0 = blockIdx.x * 64;
    const int ar = tid >> 3, ac4 = tid & 7;     // A-staging: row ar, float4-quad ac4

    f32x4 acc[4][3];
    #pragma unroll
    for (int mi = 0; mi < 4; mi++)
        #pragma unroll
        for (int ni = 0; ni < 3; ni++)
            acc[mi][ni] = (f32x4){0.f, 0.f, 0.f, 0.f};

    float4 areg;

    // prologue: stage chunk 0
    {
        const char* wb = (const char*)wsW + w * 1024 + lane * 16;
        char* db = (char*)(&Bs[0][0]) + w * 1024;
        #pragma unroll
        for (int i = 0; i < 3; i++) gload16(wb + i * 8192, db + i * 8192);
        areg = *(const float4*)(x + (size_t)(n0 + ar) * CH + ac4 * 4);
        bf16x4 t; t[0] = (bf16)areg.x; t[1] = (bf16)areg.y;
                  t[2] = (bf16)areg.z; t[3] = (bf16)areg.w;
        *(bf16x4*)&As[0][ar][ac4 * 4] = t;
        __syncthreads();
    }

    for (int c = 0; c < 16; c++) {
        const int cur = c & 1, nxt = cur ^ 1;
        if (c < 15) {
            const char* wb = (const char*)wsW + (size_t)(c + 1) * 24576 + w * 1024 + lane * 16;
            char* db = (char*)(&Bs[nxt][0]) + w * 1024;
            #pragma unroll
            for (int i = 0; i < 3; i++) gload16(wb + i * 8192, db + i * 8192);
            areg = *(const float4*)(x + (size_t)(n0 + ar) * CH + (c + 1) * 32 + ac4 * 4);
        }
        bf16x8 af[4], bf_[3];
        #pragma unroll
        for (int mi = 0; mi < 4; mi++)
            af[mi] = *(const bf16x8*)&As[cur][mi * 16 + lr][lh * 8];
        #pragma unroll
        for (int ni = 0; ni < 3; ni++) {
            int j = w * 48 + ni * 16 + lr;
            int g = lh ^ ((j >> 1) & 3);
            bf_[ni] = *(const bf16x8*)&Bs[cur][j * 32 + (g << 3)];
        }
        #pragma unroll
        for (int mi = 0; mi < 4; mi++)
            #pragma unroll
            for (int ni = 0; ni < 3; ni++)
                acc[mi][ni] = __builtin_amdgcn_mfma_f32_16x16x32_bf16(
                    af[mi], bf_[ni], acc[mi][ni], 0, 0, 0);
        if (c < 15) {
            bf16x4 t; t[0] = (bf16)areg.x; t[1] = (bf16)areg.y;
                      t[2] = (bf16)areg.z; t[3] = (bf16)areg.w;
            *(bf16x4*)&As[nxt][ar][ac4 * 4] = t;
        }
        __syncthreads();
    }

    // epilogue: write bf16 q/k/v + sum of squares (fp32, pre-quantization)
    float sq = 0.f, sk = 0.f;
    #pragma unroll
    for (int mi = 0; mi < 4; mi++) {
        #pragma unroll
        for (int ni = 0; ni < 3; ni++) {
            int col = w * 48 + ni * 16 + lr;
            int arr = col >> 7, cc = col & 127;
            bf16* dst = (arr == 0) ? qo : (arr == 1) ? ko : vo;
            #pragma unroll
            for (int r = 0; r < 4; r++) {
                int row = n0 + mi * 16 + lh * 4 + r;
                float val = acc[mi][ni][r];
                dst[(size_t)row * HD + cc] = (bf16)val;
                if (arr == 0) sq += val * val;
                else if (arr == 1) sk += val * val;
            }
        }
    }
    #pragma unroll
    for (int off = 32; off > 0; off >>= 1) {
        sq += __shfl_down(sq, off);
        sk += __shfl_down(sk, off);
    }
    if (lane == 0) { rq[w] = sq; rk[w] = sk; }
    __syncthreads();
    if (tid == 0) {
        float a = 0.f, b = 0.f;
        #pragma unroll
        for (int i = 0; i < 8; i++) { a += rq[i]; b += rk[i]; }
        atomicAdd(&sumsq[0], a);
        atomicAdd(&sumsq[1], b);
    }
}

// ---------------- K2: per-graph k^T v via MFMA (node-dim as K) ----------------
// grid 256 blocks (16 graphs x 16 chunks of 512 rows) x 512 threads (8 waves, 2x4).
__global__ __launch_bounds__(512, 1) void k2_kv(
    const bf16* __restrict__ ko, const bf16* __restrict__ vo,
    float* __restrict__ part_kv, float* __restrict__ part_ks)
{
    __shared__ __align__(16) char smem[16640];   // kt[32][130] | vt[32][130]; reused as f32 scr
    bf16 (*kt)[130] = (bf16(*)[130])smem;
    bf16 (*vt)[130] = (bf16(*)[130])(smem + 8320);
    float* scr = (float*)smem;

    const int tid = threadIdx.x, lane = tid & 63, w = tid >> 6;
    const int wr = w >> 2, wc = w & 3;           // 2 m-groups x 4 d-groups
    const int lr = lane & 15, lh = lane >> 4;
    const int b = blockIdx.x >> 4, cch = blockIdx.x & 15;
    const size_t l0 = (size_t)b * LMAX + (size_t)cch * 512;
    const int sr = tid >> 4, sc = tid & 15;      // staging row / col8

    f32x4 acc[4][2];
    #pragma unroll
    for (int mi = 0; mi < 4; mi++)
        #pragma unroll
        for (int ni = 0; ni < 2; ni++)
            acc[mi][ni] = (f32x4){0.f, 0.f, 0.f, 0.f};
    float ks8[8] = {};

    uint4 kk4 = *(const uint4*)&ko[(l0 + sr) * HD + sc * 8];
    uint4 vv4 = *(const uint4*)&vo[(l0 + sr) * HD + sc * 8];

    for (int lt = 0; lt < 512; lt += 32) {
        __syncthreads();   // prev compute done
        #pragma unroll
        for (int j2 = 0; j2 < 4; j2++) {
            *(unsigned int*)&kt[sr][sc * 8 + j2 * 2] = ((const unsigned int*)&kk4)[j2];
            *(unsigned int*)&vt[sr][sc * 8 + j2 * 2] = ((const unsigned int*)&vv4)[j2];
        }
        #pragma unroll
        for (int j = 0; j < 8; j++) ks8[j] += (float)((const bf16*)&kk4)[j];
        __syncthreads();   // tiles published
        if (lt + 32 < 512) {   // prefetch next tile during compute
            kk4 = *(const uint4*)&ko[(l0 + lt + 32 + sr) * HD + sc * 8];
            vv4 = *(const uint4*)&vo[(l0 + lt + 32 + sr) * HD + sc * 8];
        }
        bf16x8 a[4], bb[2];
        #pragma unroll
        for (int mi = 0; mi < 4; mi++) {
            int m = wr * 64 + mi * 16 + lr;
            #pragma unroll
            for (int j = 0; j < 8; j++) a[mi][j] = kt[lh * 8 + j][m];
        }
        #pragma unroll
        for (int ni = 0; ni < 2; ni++) {
            int d = wc * 32 + ni * 16 + lr;
            #pragma unroll
            for (int j = 0; j < 8; j++) bb[ni][j] = vt[lh * 8 + j][d];
        }
        #pragma unroll
        for (int mi = 0; mi < 4; mi++)
            #pragma unroll
            for (int ni = 0; ni < 2; ni++)
                acc[mi][ni] = __builtin_amdgcn_mfma_f32_16x16x32_bf16(
                    a[mi], bb[ni], acc[mi][ni], 0, 0, 0);
    }

    // ks partial: reduce per-thread col-sums across the 32 row-groups
    __syncthreads();
    #pragma unroll
    for (int j = 0; j < 8; j++) scr[tid * 8 + j] = ks8[j];
    __syncthreads();
    if (tid < 128) {
        float s = 0.f;
        #pragma unroll
        for (int g = 0; g < 32; g++)
            s += scr[((g << 4) | (tid >> 3)) * 8 + (tid & 7)];
        part_ks[blockIdx.x * HD + tid] = s;
    }

    float* dst = part_kv + (size_t)blockIdx.x * 16384;
    #pragma unroll
    for (int mi = 0; mi < 4; mi++)
        #pragma unroll
        for (int ni = 0; ni < 2; ni++)
            #pragma unroll
            for (int r = 0; r < 4; r++) {
                int m = wr * 64 + mi * 16 + lh * 4 + r;
                int d = wc * 32 + ni * 16 + lr;
                dst[m * HD + d] = acc[mi][ni][r];
            }
}

// ---------------- K2b: reduce 16 partials/graph, apply s_q*s_k, write kvs^T ----------------
__global__ __launch_bounds__(256, 1) void k2b_reduce(
    const float* __restrict__ part_kv, const float* __restrict__ part_ks,
    const float* __restrict__ sumsq,
    bf16* __restrict__ kvsT, float* __restrict__ ks_sum_s)
{
    const int b = blockIdx.x >> 3, ms = blockIdx.x & 7, tid = threadIdx.x;
    const float s_qk = rsqrtf(sumsq[0]) * rsqrtf(sumsq[1]);

    #pragma unroll
    for (int i = 0; i < 8; i++) {
        int idx = i * 256 + tid;               // 2048 outputs for this m-slice
        int m = ms * 16 + (idx >> 7), d = idx & 127;
        float s = 0.f;
        #pragma unroll
        for (int c = 0; c < 16; c++)
            s += part_kv[((size_t)(b * 16 + c) << 14) + (m << 7) + d];
        kvsT[((size_t)b << 14) + (d << 7) + m] = (bf16)(s * s_qk);
    }
    if (ms == 0 && tid < 128) {
        float s = 0.f;
        #pragma unroll
        for (int c = 0; c < 16; c++)
            s += part_ks[(b * 16 + c) * HD + tid];
        ks_sum_s[b * HD + tid] = s * s_qk;
    }
}

// ---------------- K3: out = (q @ kvsT + 16 v) / (q . ks_sum_s + 16) ----------------
// 70 KB LDS -> 2 blocks/CU; kvsT B-frags read direct from global (L2-hot, 32 KB/graph).
__global__ __launch_bounds__(256, 2) void k3_out(
    const bf16* __restrict__ qo, const bf16* __restrict__ vo,
    const bf16* __restrict__ kvsT, const float* __restrict__ ks_sum_s,
    float* __restrict__ out)
{
    __shared__ bf16 qs[128][136];
    __shared__ bf16 vsh[128][136];
    __shared__ float kss[128];
    __shared__ float denom[128];
    const int tid = threadIdx.x, lane = tid & 63, w = tid >> 6;
    const int lr = lane & 15, lh = lane >> 4;
    const int n0 = blockIdx.x * 128;
    const int b = n0 >> 13;

    #pragma unroll
    for (int i = 0; i < 8; i++) {
        int idx = tid + i * 256;
        int r = idx >> 4, c8 = idx & 15;
        *(bf16x8*)&qs[r][c8 * 8]  = *(const bf16x8*)&qo[(size_t)(n0 + r) * HD + c8 * 8];
        *(bf16x8*)&vsh[r][c8 * 8] = *(const bf16x8*)&vo[(size_t)(n0 + r) * HD + c8 * 8];
    }
    if (tid < 128) kss[tid] = ks_sum_s[b * HD + tid];
    __syncthreads();

    if (tid < 128) {
        float s = 0.f;
        #pragma unroll 8
        for (int m = 0; m < HD; m++) s += (float)qs[tid][m] * kss[m];
        denom[tid] = s + 16.0f;
    }

    f32x4 acc[2][8];
    #pragma unroll
    for (int mi = 0; mi < 2; mi++)
        #pragma unroll
        for (int ni = 0; ni < 8; ni++)
            acc[mi][ni] = (f32x4){0.f, 0.f, 0.f, 0.f};

    #pragma unroll
    for (int k0 = 0; k0 < HD; k0 += 32) {
        bf16x8 a[2], bb[8];
        #pragma unroll
        for (int mi = 0; mi < 2; mi++)
            a[mi] = *(const bf16x8*)&qs[w * 32 + mi * 16 + lr][k0 + lh * 8];
        #pragma unroll
        for (int ni = 0; ni < 8; ni++)
            bb[ni] = *(const bf16x8*)&kvsT[(size_t)b * 16384 + (size_t)(ni * 16 + lr) * HD + k0 + lh * 8];
        #pragma unroll
        for (int mi = 0; mi < 2; mi++)
            #pragma unroll
            for (int ni = 0; ni < 8; ni++)
                acc[mi][ni] = __builtin_amdgcn_mfma_f32_16x16x32_bf16(
                    a[mi], bb[ni], acc[mi][ni], 0, 0, 0);
    }
    __syncthreads();   // denom ready

    #pragma unroll
    for (int mi = 0; mi < 2; mi++) {
        #pragma unroll
        for (int ni = 0; ni < 8; ni++) {
            int col = ni * 16 + lr;
            #pragma unroll
            for (int r = 0; r < 4; r++) {
                int row = w * 32 + mi * 16 + lh * 4 + r;
                float vv = (float)vsh[row][col];
                out[(size_t)(n0 + row) * HD + col] =
                    (acc[mi][ni][r] + 16.0f * vv) / denom[row];
            }
        }
    }
}

// ---------------- launch ----------------
extern "C" void kernel_launch(void* const* d_in, const int* in_sizes, int n_in,
                              void* d_out, int out_size, void* d_ws, size_t ws_size,
                              hipStream_t stream)
{
    const float* x  = (const float*)d_in[0];
    const float* Wq = (const float*)d_in[1];
    const float* Wk = (const float*)d_in[2];
    const float* Wv = (const float*)d_in[3];

    char* ws = (char*)d_ws;
    const size_t Q_OFF   = 0;                       // 131072*128*2 = 33554432
    const size_t K_OFF   = 33554432;
    const size_t V_OFF   = 67108864;
    const size_t PKV_OFF = 100663296;               // 256*16384*4 = 16777216
    const size_t PKS_OFF = 117440512;               // 256*128*4   = 131072
    const size_t KVS_OFF = 117571584;               // 16*16384*2  = 524288
    const size_t KSS_OFF = 118095872;               // 16*128*4    = 8192
    const size_t SSQ_OFF = 118104064;               // 2*4
    const size_t NEED    = 118104072;
    if (ws_size < NEED) return;

    bf16*  qo      = (bf16*)(ws + Q_OFF);
    bf16*  ko      = (bf16*)(ws + K_OFF);
    bf16*  vo      = (bf16*)(ws + V_OFF);
    float* part_kv = (float*)(ws + PKV_OFF);
    float* part_ks = (float*)(ws + PKS_OFF);
    bf16*  kvsT    = (bf16*)(ws + KVS_OFF);
    float* ks_sum  = (float*)(ws + KSS_OFF);
    float* sumsq   = (float*)(ws + SSQ_OFF);
    // wsW (393216 B) overlaps part_kv region: live only k0->k1, dead before k2 writes part_kv
    bf16*  wsW     = (bf16*)(ws + PKV_OFF);

    hipMemsetAsync(sumsq, 0, 8, stream);
    k0_prep<<<dim3(96), dim3(256), 0, stream>>>(Wq, Wk, Wv, wsW);
    k1_proj<<<dim3(N_NODES / 64), dim3(512), 0, stream>>>(x, wsW, qo, ko, vo, sumsq);
    k2_kv<<<dim3(256), dim3(512), 0, stream>>>(ko, vo, part_kv, part_ks);
    k2b_reduce<<<dim3(128), dim3(256), 0, stream>>>(part_kv, part_ks, sumsq, kvsT, ks_sum);
    k3_out<<<dim3(N_NODES / 128), dim3(256), 0, stream>>>(qo, vo, kvsT, ks_sum, (float*)d_out);
}

// Round 10
// 202.150 us; speedup vs baseline: 1.7493x; 1.2608x over previous
//
#include <hip/hip_runtime.h>
#include <hip/hip_bf16.h>

typedef __bf16 bf16;
typedef __bf16 bf16x4 __attribute__((ext_vector_type(4)));
typedef __bf16 bf16x8 __attribute__((ext_vector_type(8)));
typedef float f32x4 __attribute__((ext_vector_type(4)));

#define N_NODES 131072
#define CH      512
#define HD      128
#define LMAX    8192
#define NG      16

typedef __attribute__((address_space(3))) unsigned int lds_u32;
typedef __attribute__((address_space(1))) const unsigned int g_u32;

__device__ __forceinline__ void gload16(const void* gp, void* lp) {
    __builtin_amdgcn_global_load_lds((g_u32*)gp, (lds_u32*)lp, 16, 0, 0);
}

// ---------------- K0: W (3x128x512 fp32) -> bf16, staging-order, inverse-XOR-swizzled ----
// wsW granule layout: [c=16][j=384][g=4] of 8 elems; value = W3[j][c*32 + ((g ^ ((j>>1)&3))<<3) + e]
// K1 reads granule g = lh ^ ((j>>1)&3) to get cols lh*8..lh*8+7.
__global__ __launch_bounds__(256, 1) void k0_prep(
    const float* __restrict__ Wq, const float* __restrict__ Wk,
    const float* __restrict__ Wv, bf16* __restrict__ wsW)
{
    int t = blockIdx.x * 256 + threadIdx.x;      // 24576 granules of 8 elements
    int c = t / 1536;                            // K-chunk (BK=32)
    int r = t % 1536;
    int j = r >> 2, g = r & 3;
    const float* Wrow = (j < 128) ? (Wq + (size_t)j * CH)
                       : (j < 256) ? (Wk + (size_t)(j - 128) * CH)
                                   : (Wv + (size_t)(j - 256) * CH);
    int col0 = c * 32 + ((g ^ ((j >> 1) & 3)) << 3);
    float4 f0 = *(const float4*)(Wrow + col0);
    float4 f1 = *(const float4*)(Wrow + col0 + 4);
    bf16x8 o;
    o[0] = (bf16)f0.x; o[1] = (bf16)f0.y; o[2] = (bf16)f0.z; o[3] = (bf16)f0.w;
    o[4] = (bf16)f1.x; o[5] = (bf16)f1.y; o[6] = (bf16)f1.z; o[7] = (bf16)f1.w;
    *(bf16x8*)(wsW + (size_t)t * 8) = o;
}

// ---------------- K1: QKV projection, 128x384 tile, BK=32, 2 blocks/CU, no spill ----------------
// grid 1024 x 512 threads; 70 KB LDS; acc 96 f32 + frag overhead ~= 120 VGPR (round-4 structure).
__global__ __launch_bounds__(512, 2) void k1_proj(
    const float* __restrict__ x, const bf16* __restrict__ wsW,
    bf16* __restrict__ qo, bf16* __restrict__ ko, bf16* __restrict__ vo,
    float* __restrict__ sumsq)
{
    __shared__ bf16 As[2][128][40];   // 20,480 B (rows 80 B: frag reads land 2 lanes/bank = free)
    __shared__ bf16 Bs[2][12288];     // 49,152 B (linear [384][32], swizzled content)
    __shared__ float rq[8], rk[8];

    const int tid = threadIdx.x;
    const int lane = tid & 63;
    const int w = tid >> 6;
    const int wr = w >> 2, wc = w & 3;          // 2x4 wave grid: 64 rows x 96 cols per wave
    const int lr = lane & 15, lh = lane >> 4;
    const int n0 = blockIdx.x * 128;
    const int ar = tid >> 2, ac = tid & 3;      // A-staging: row ar, col-octet ac (8 floats)

    f32x4 acc[4][6];
    #pragma unroll
    for (int mi = 0; mi < 4; mi++)
        #pragma unroll
        for (int ni = 0; ni < 6; ni++)
            acc[mi][ni] = (f32x4){0.f, 0.f, 0.f, 0.f};

    float4 areg0, areg1;

    // prologue: stage chunk 0
    {
        const char* wb = (const char*)wsW + w * 1024 + lane * 16;
        char* db = (char*)(&Bs[0][0]) + w * 1024;
        #pragma unroll
        for (int i = 0; i < 3; i++) gload16(wb + i * 8192, db + i * 8192);
        areg0 = *(const float4*)(x + (size_t)(n0 + ar) * CH + ac * 8);
        areg1 = *(const float4*)(x + (size_t)(n0 + ar) * CH + ac * 8 + 4);
        bf16x8 t;
        t[0] = (bf16)areg0.x; t[1] = (bf16)areg0.y; t[2] = (bf16)areg0.z; t[3] = (bf16)areg0.w;
        t[4] = (bf16)areg1.x; t[5] = (bf16)areg1.y; t[6] = (bf16)areg1.z; t[7] = (bf16)areg1.w;
        *(bf16x8*)&As[0][ar][ac * 8] = t;
        __syncthreads();
    }

    for (int c = 0; c < 16; c++) {
        const int cur = c & 1, nxt = cur ^ 1;
        if (c < 15) {
            // issue next chunk's loads BEFORE compute (latency hides under MFMAs + other block)
            const char* wb = (const char*)wsW + (size_t)(c + 1) * 24576 + w * 1024 + lane * 16;
            char* db = (char*)(&Bs[nxt][0]) + w * 1024;
            #pragma unroll
            for (int i = 0; i < 3; i++) gload16(wb + i * 8192, db + i * 8192);
            areg0 = *(const float4*)(x + (size_t)(n0 + ar) * CH + (c + 1) * 32 + ac * 8);
            areg1 = *(const float4*)(x + (size_t)(n0 + ar) * CH + (c + 1) * 32 + ac * 8 + 4);
        }
        bf16x8 af[4];
        #pragma unroll
        for (int mi = 0; mi < 4; mi++)
            af[mi] = *(const bf16x8*)&As[cur][wr * 64 + mi * 16 + lr][lh * 8];
        #pragma unroll
        for (int mi = 0; mi < 4; mi++) {
            #pragma unroll
            for (int ni = 0; ni < 6; ni++) {
                int j = wc * 96 + ni * 16 + lr;
                int g = lh ^ ((j >> 1) & 3);
                bf16x8 bf_ = *(const bf16x8*)&Bs[cur][j * 32 + (g << 3)];
                acc[mi][ni] = __builtin_amdgcn_mfma_f32_16x16x32_bf16(
                    af[mi], bf_, acc[mi][ni], 0, 0, 0);
            }
        }
        if (c < 15) {
            bf16x8 t;
            t[0] = (bf16)areg0.x; t[1] = (bf16)areg0.y; t[2] = (bf16)areg0.z; t[3] = (bf16)areg0.w;
            t[4] = (bf16)areg1.x; t[5] = (bf16)areg1.y; t[6] = (bf16)areg1.z; t[7] = (bf16)areg1.w;
            *(bf16x8*)&As[nxt][ar][ac * 8] = t;
        }
        __syncthreads();
    }

    // epilogue: write bf16 q/k/v + sum of squares (fp32, pre-quantization)
    float sq = 0.f, sk = 0.f;
    #pragma unroll
    for (int mi = 0; mi < 4; mi++) {
        #pragma unroll
        for (int ni = 0; ni < 6; ni++) {
            int col = wc * 96 + ni * 16 + lr;
            int arr = col >> 7, cc = col & 127;
            bf16* dst = (arr == 0) ? qo : (arr == 1) ? ko : vo;
            #pragma unroll
            for (int r = 0; r < 4; r++) {
                int row = n0 + wr * 64 + mi * 16 + lh * 4 + r;
                float val = acc[mi][ni][r];
                dst[(size_t)row * HD + cc] = (bf16)val;
                if (arr == 0) sq += val * val;
                else if (arr == 1) sk += val * val;
            }
        }
    }
    #pragma unroll
    for (int off = 32; off > 0; off >>= 1) {
        sq += __shfl_down(sq, off);
        sk += __shfl_down(sk, off);
    }
    if (lane == 0) { rq[w] = sq; rk[w] = sk; }
    __syncthreads();
    if (tid == 0) {
        float a = 0.f, b = 0.f;
        #pragma unroll
        for (int i = 0; i < 8; i++) { a += rq[i]; b += rk[i]; }
        atomicAdd(&sumsq[0], a);
        atomicAdd(&sumsq[1], b);
    }
}

// ---------------- K2: per-graph k^T v via MFMA (node-dim as K) ----------------
// grid 256 blocks (16 graphs x 16 chunks of 512 rows) x 512 threads (8 waves, 2x4).
__global__ __launch_bounds__(512, 1) void k2_kv(
    const bf16* __restrict__ ko, const bf16* __restrict__ vo,
    float* __restrict__ part_kv, float* __restrict__ part_ks)
{
    __shared__ __align__(16) char smem[16640];   // kt[32][130] | vt[32][130]; reused as f32 scr
    bf16 (*kt)[130] = (bf16(*)[130])smem;
    bf16 (*vt)[130] = (bf16(*)[130])(smem + 8320);
    float* scr = (float*)smem;

    const int tid = threadIdx.x, lane = tid & 63, w = tid >> 6;
    const int wr = w >> 2, wc = w & 3;           // 2 m-groups x 4 d-groups
    const int lr = lane & 15, lh = lane >> 4;
    const int b = blockIdx.x >> 4, cch = blockIdx.x & 15;
    const size_t l0 = (size_t)b * LMAX + (size_t)cch * 512;
    const int sr = tid >> 4, sc = tid & 15;      // staging row / col8

    f32x4 acc[4][2];
    #pragma unroll
    for (int mi = 0; mi < 4; mi++)
        #pragma unroll
        for (int ni = 0; ni < 2; ni++)
            acc[mi][ni] = (f32x4){0.f, 0.f, 0.f, 0.f};
    float ks8[8] = {};

    uint4 kk4 = *(const uint4*)&ko[(l0 + sr) * HD + sc * 8];
    uint4 vv4 = *(const uint4*)&vo[(l0 + sr) * HD + sc * 8];

    for (int lt = 0; lt < 512; lt += 32) {
        __syncthreads();   // prev compute done
        #pragma unroll
        for (int j2 = 0; j2 < 4; j2++) {
            *(unsigned int*)&kt[sr][sc * 8 + j2 * 2] = ((const unsigned int*)&kk4)[j2];
            *(unsigned int*)&vt[sr][sc * 8 + j2 * 2] = ((const unsigned int*)&vv4)[j2];
        }
        #pragma unroll
        for (int j = 0; j < 8; j++) ks8[j] += (float)((const bf16*)&kk4)[j];
        __syncthreads();   // tiles published
        if (lt + 32 < 512) {   // prefetch next tile during compute
            kk4 = *(const uint4*)&ko[(l0 + lt + 32 + sr) * HD + sc * 8];
            vv4 = *(const uint4*)&vo[(l0 + lt + 32 + sr) * HD + sc * 8];
        }
        bf16x8 a[4], bb[2];
        #pragma unroll
        for (int mi = 0; mi < 4; mi++) {
            int m = wr * 64 + mi * 16 + lr;
            #pragma unroll
            for (int j = 0; j < 8; j++) a[mi][j] = kt[lh * 8 + j][m];
        }
        #pragma unroll
        for (int ni = 0; ni < 2; ni++) {
            int d = wc * 32 + ni * 16 + lr;
            #pragma unroll
            for (int j = 0; j < 8; j++) bb[ni][j] = vt[lh * 8 + j][d];
        }
        #pragma unroll
        for (int mi = 0; mi < 4; mi++)
            #pragma unroll
            for (int ni = 0; ni < 2; ni++)
                acc[mi][ni] = __builtin_amdgcn_mfma_f32_16x16x32_bf16(
                    a[mi], bb[ni], acc[mi][ni], 0, 0, 0);
    }

    // ks partial: reduce per-thread col-sums across the 32 row-groups
    __syncthreads();
    #pragma unroll
    for (int j = 0; j < 8; j++) scr[tid * 8 + j] = ks8[j];
    __syncthreads();
    if (tid < 128) {
        float s = 0.f;
        #pragma unroll
        for (int g = 0; g < 32; g++)
            s += scr[((g << 4) | (tid >> 3)) * 8 + (tid & 7)];
        part_ks[blockIdx.x * HD + tid] = s;
    }

    float* dst = part_kv + (size_t)blockIdx.x * 16384;
    #pragma unroll
    for (int mi = 0; mi < 4; mi++)
        #pragma unroll
        for (int ni = 0; ni < 2; ni++)
            #pragma unroll
            for (int r = 0; r < 4; r++) {
                int m = wr * 64 + mi * 16 + lh * 4 + r;
                int d = wc * 32 + ni * 16 + lr;
                dst[m * HD + d] = acc[mi][ni][r];
            }
}

// ---------------- K2b: reduce 16 partials/graph, apply s_q*s_k, write kvs^T ----------------
__global__ __launch_bounds__(256, 1) void k2b_reduce(
    const float* __restrict__ part_kv, const float* __restrict__ part_ks,
    const float* __restrict__ sumsq,
    bf16* __restrict__ kvsT, float* __restrict__ ks_sum_s)
{
    const int b = blockIdx.x >> 3, ms = blockIdx.x & 7, tid = threadIdx.x;
    const float s_qk = rsqrtf(sumsq[0]) * rsqrtf(sumsq[1]);

    #pragma unroll
    for (int i = 0; i < 8; i++) {
        int idx = i * 256 + tid;               // 2048 outputs for this m-slice
        int m = ms * 16 + (idx >> 7), d = idx & 127;
        float s = 0.f;
        #pragma unroll
        for (int c = 0; c < 16; c++)
            s += part_kv[((size_t)(b * 16 + c) << 14) + (m << 7) + d];
        kvsT[((size_t)b << 14) + (d << 7) + m] = (bf16)(s * s_qk);
    }
    if (ms == 0 && tid < 128) {
        float s = 0.f;
        #pragma unroll
        for (int c = 0; c < 16; c++)
            s += part_ks[(b * 16 + c) * HD + tid];
        ks_sum_s[b * HD + tid] = s * s_qk;
    }
}

// ---------------- K3: out = (q @ kvsT + 16 v) / (q . ks_sum_s + 16) ----------------
// 70 KB LDS -> 2 blocks/CU; kvsT B-frags read direct from global (L2-hot, 32 KB/graph).
__global__ __launch_bounds__(256, 2) void k3_out(
    const bf16* __restrict__ qo, const bf16* __restrict__ vo,
    const bf16* __restrict__ kvsT, const float* __restrict__ ks_sum_s,
    float* __restrict__ out)
{
    __shared__ bf16 qs[128][136];
    __shared__ bf16 vsh[128][136];
    __shared__ float kss[128];
    __shared__ float denom[128];
    const int tid = threadIdx.x, lane = tid & 63, w = tid >> 6;
    const int lr = lane & 15, lh = lane >> 4;
    const int n0 = blockIdx.x * 128;
    const int b = n0 >> 13;

    #pragma unroll
    for (int i = 0; i < 8; i++) {
        int idx = tid + i * 256;
        int r = idx >> 4, c8 = idx & 15;
        *(bf16x8*)&qs[r][c8 * 8]  = *(const bf16x8*)&qo[(size_t)(n0 + r) * HD + c8 * 8];
        *(bf16x8*)&vsh[r][c8 * 8] = *(const bf16x8*)&vo[(size_t)(n0 + r) * HD + c8 * 8];
    }
    if (tid < 128) kss[tid] = ks_sum_s[b * HD + tid];
    __syncthreads();

    if (tid < 128) {
        float s = 0.f;
        #pragma unroll 8
        for (int m = 0; m < HD; m++) s += (float)qs[tid][m] * kss[m];
        denom[tid] = s + 16.0f;
    }

    f32x4 acc[2][8];
    #pragma unroll
    for (int mi = 0; mi < 2; mi++)
        #pragma unroll
        for (int ni = 0; ni < 8; ni++)
            acc[mi][ni] = (f32x4){0.f, 0.f, 0.f, 0.f};

    #pragma unroll
    for (int k0 = 0; k0 < HD; k0 += 32) {
        bf16x8 a[2], bb[8];
        #pragma unroll
        for (int mi = 0; mi < 2; mi++)
            a[mi] = *(const bf16x8*)&qs[w * 32 + mi * 16 + lr][k0 + lh * 8];
        #pragma unroll
        for (int ni = 0; ni < 8; ni++)
            bb[ni] = *(const bf16x8*)&kvsT[(size_t)b * 16384 + (size_t)(ni * 16 + lr) * HD + k0 + lh * 8];
        #pragma unroll
        for (int mi = 0; mi < 2; mi++)
            #pragma unroll
            for (int ni = 0; ni < 8; ni++)
                acc[mi][ni] = __builtin_amdgcn_mfma_f32_16x16x32_bf16(
                    a[mi], bb[ni], acc[mi][ni], 0, 0, 0);
    }
    __syncthreads();   // denom ready

    #pragma unroll
    for (int mi = 0; mi < 2; mi++) {
        #pragma unroll
        for (int ni = 0; ni < 8; ni++) {
            int col = ni * 16 + lr;
            #pragma unroll
            for (int r = 0; r < 4; r++) {
                int row = w * 32 + mi * 16 + lh * 4 + r;
                float vv = (float)vsh[row][col];
                out[(size_t)(n0 + row) * HD + col] =
                    (acc[mi][ni][r] + 16.0f * vv) / denom[row];
            }
        }
    }
}

// ---------------- launch ----------------
extern "C" void kernel_launch(void* const* d_in, const int* in_sizes, int n_in,
                              void* d_out, int out_size, void* d_ws, size_t ws_size,
                              hipStream_t stream)
{
    const float* x  = (const float*)d_in[0];
    const float* Wq = (const float*)d_in[1];
    const float* Wk = (const float*)d_in[2];
    const float* Wv = (const float*)d_in[3];

    char* ws = (char*)d_ws;
    const size_t Q_OFF   = 0;                       // 131072*128*2 = 33554432
    const size_t K_OFF   = 33554432;
    const size_t V_OFF   = 67108864;
    const size_t PKV_OFF = 100663296;               // 256*16384*4 = 16777216
    const size_t PKS_OFF = 117440512;               // 256*128*4   = 131072
    const size_t KVS_OFF = 117571584;               // 16*16384*2  = 524288
    const size_t KSS_OFF = 118095872;               // 16*128*4    = 8192
    const size_t SSQ_OFF = 118104064;               // 2*4
    const size_t NEED    = 118104072;
    if (ws_size < NEED) return;

    bf16*  qo      = (bf16*)(ws + Q_OFF);
    bf16*  ko      = (bf16*)(ws + K_OFF);
    bf16*  vo      = (bf16*)(ws + V_OFF);
    float* part_kv = (float*)(ws + PKV_OFF);
    float* part_ks = (float*)(ws + PKS_OFF);
    bf16*  kvsT    = (bf16*)(ws + KVS_OFF);
    float* ks_sum  = (float*)(ws + KSS_OFF);
    float* sumsq   = (float*)(ws + SSQ_OFF);
    // wsW (393216 B) overlaps part_kv region: live only k0->k1, dead before k2 writes part_kv
    bf16*  wsW     = (bf16*)(ws + PKV_OFF);

    hipMemsetAsync(sumsq, 0, 8, stream);
    k0_prep<<<dim3(96), dim3(256), 0, stream>>>(Wq, Wk, Wv, wsW);
    k1_proj<<<dim3(N_NODES / 128), dim3(512), 0, stream>>>(x, wsW, qo, ko, vo, sumsq);
    k2_kv<<<dim3(256), dim3(512), 0, stream>>>(ko, vo, part_kv, part_ks);
    k2b_reduce<<<dim3(128), dim3(256), 0, stream>>>(part_kv, part_ks, sumsq, kvsT, ks_sum);
    k3_out<<<dim3(N_NODES / 128), dim3(256), 0, stream>>>(qo, vo, kvsT, ks_sum, (float*)d_out);
}

// Round 11
// 199.541 us; speedup vs baseline: 1.7722x; 1.0131x over previous
//
#include <hip/hip_runtime.h>
#include <hip/hip_bf16.h>

typedef __bf16 bf16;
typedef __bf16 bf16x4 __attribute__((ext_vector_type(4)));
typedef __bf16 bf16x8 __attribute__((ext_vector_type(8)));
typedef float f32x4 __attribute__((ext_vector_type(4)));

#define N_NODES 131072
#define CH      512
#define HD      128
#define LMAX    8192
#define NG      16

typedef __attribute__((address_space(3))) unsigned int lds_u32;
typedef __attribute__((address_space(1))) const unsigned int g_u32;

__device__ __forceinline__ void gload16(const void* gp, void* lp) {
    __builtin_amdgcn_global_load_lds((g_u32*)gp, (lds_u32*)lp, 16, 0, 0);
}

// ---------------- K0: W (3x128x512 fp32) -> bf16, staging-order, inverse-XOR-swizzled ----
// wsW granule layout: [c=16][j=384][g=4] of 8 elems; value = W3[j][c*32 + ((g ^ ((j>>1)&3))<<3) + e]
// K1 reads granule g = lh ^ ((j>>1)&3) to get cols lh*8..lh*8+7.
__global__ __launch_bounds__(256, 1) void k0_prep(
    const float* __restrict__ Wq, const float* __restrict__ Wk,
    const float* __restrict__ Wv, bf16* __restrict__ wsW)
{
    int t = blockIdx.x * 256 + threadIdx.x;      // 24576 granules of 8 elements
    int c = t / 1536;                            // K-chunk (BK=32)
    int r = t % 1536;
    int j = r >> 2, g = r & 3;
    const float* Wrow = (j < 128) ? (Wq + (size_t)j * CH)
                       : (j < 256) ? (Wk + (size_t)(j - 128) * CH)
                                   : (Wv + (size_t)(j - 256) * CH);
    int col0 = c * 32 + ((g ^ ((j >> 1) & 3)) << 3);
    float4 f0 = *(const float4*)(Wrow + col0);
    float4 f1 = *(const float4*)(Wrow + col0 + 4);
    bf16x8 o;
    o[0] = (bf16)f0.x; o[1] = (bf16)f0.y; o[2] = (bf16)f0.z; o[3] = (bf16)f0.w;
    o[4] = (bf16)f1.x; o[5] = (bf16)f1.y; o[6] = (bf16)f1.z; o[7] = (bf16)f1.w;
    *(bf16x8*)(wsW + (size_t)t * 8) = o;
}

// ---------------- K1: QKV projection, 64x384 tile, 4 waves, BK=32 dbuf ----------------
// grid 2048 x 256 threads; __launch_bounds__(256,2): 2 blocks/CU = 2 waves/SIMD -> 256-VGPR cap.
// Headroom lets all 4 A-frags + 6 B-frags hoist -> 24 back-to-back MFMAs per chunk.
__global__ __launch_bounds__(256, 2) void k1_proj(
    const float* __restrict__ x, const bf16* __restrict__ wsW,
    bf16* __restrict__ qo, bf16* __restrict__ ko, bf16* __restrict__ vo,
    float* __restrict__ sumsq)
{
    __shared__ bf16 As[2][64][40];    // 10,240 B (pad 8)
    __shared__ bf16 Bs[2][12288];     // 49,152 B (linear [384][32], swizzled content)
    __shared__ float rq[4], rk[4];

    const int tid = threadIdx.x;
    const int lane = tid & 63;
    const int w = tid >> 6;                     // 4 waves: wave w -> cols w*96..w*96+95
    const int lr = lane & 15, lh = lane >> 4;
    const int n0 = blockIdx.x * 64;
    const int ar = tid >> 3, ac = tid & 7;      // A-staging: rows ar, ar+32; float4 ac

    f32x4 acc[4][6];
    #pragma unroll
    for (int mi = 0; mi < 4; mi++)
        #pragma unroll
        for (int ni = 0; ni < 6; ni++)
            acc[mi][ni] = (f32x4){0.f, 0.f, 0.f, 0.f};

    float4 areg0, areg1;

    // prologue: stage chunk 0
    {
        const char* wb = (const char*)wsW + w * 1024 + lane * 16;
        char* db = (char*)(&Bs[0][0]) + w * 1024;
        #pragma unroll
        for (int i = 0; i < 6; i++) gload16(wb + i * 4096, db + i * 4096);
        areg0 = *(const float4*)(x + (size_t)(n0 + ar) * CH + ac * 4);
        areg1 = *(const float4*)(x + (size_t)(n0 + ar + 32) * CH + ac * 4);
        bf16x4 t0, t1;
        t0[0] = (bf16)areg0.x; t0[1] = (bf16)areg0.y; t0[2] = (bf16)areg0.z; t0[3] = (bf16)areg0.w;
        t1[0] = (bf16)areg1.x; t1[1] = (bf16)areg1.y; t1[2] = (bf16)areg1.z; t1[3] = (bf16)areg1.w;
        *(bf16x4*)&As[0][ar][ac * 4] = t0;
        *(bf16x4*)&As[0][ar + 32][ac * 4] = t1;
        __syncthreads();
    }

    for (int c = 0; c < 16; c++) {
        const int cur = c & 1, nxt = cur ^ 1;
        if (c < 15) {
            // issue next chunk's loads BEFORE compute (latency hides under MFMA burst)
            const char* wb = (const char*)wsW + (size_t)(c + 1) * 24576 + w * 1024 + lane * 16;
            char* db = (char*)(&Bs[nxt][0]) + w * 1024;
            #pragma unroll
            for (int i = 0; i < 6; i++) gload16(wb + i * 4096, db + i * 4096);
            areg0 = *(const float4*)(x + (size_t)(n0 + ar) * CH + (c + 1) * 32 + ac * 4);
            areg1 = *(const float4*)(x + (size_t)(n0 + ar + 32) * CH + (c + 1) * 32 + ac * 4);
        }
        // hoist ALL fragments, then a pure-MFMA burst (needs the 256-VGPR budget)
        bf16x8 af[4], bf_[6];
        #pragma unroll
        for (int mi = 0; mi < 4; mi++)
            af[mi] = *(const bf16x8*)&As[cur][mi * 16 + lr][lh * 8];
        #pragma unroll
        for (int ni = 0; ni < 6; ni++) {
            int j = w * 96 + ni * 16 + lr;
            int g = lh ^ ((j >> 1) & 3);
            bf_[ni] = *(const bf16x8*)&Bs[cur][j * 32 + (g << 3)];
        }
        #pragma unroll
        for (int mi = 0; mi < 4; mi++)
            #pragma unroll
            for (int ni = 0; ni < 6; ni++)
                acc[mi][ni] = __builtin_amdgcn_mfma_f32_16x16x32_bf16(
                    af[mi], bf_[ni], acc[mi][ni], 0, 0, 0);
        if (c < 15) {
            bf16x4 t0, t1;
            t0[0] = (bf16)areg0.x; t0[1] = (bf16)areg0.y; t0[2] = (bf16)areg0.z; t0[3] = (bf16)areg0.w;
            t1[0] = (bf16)areg1.x; t1[1] = (bf16)areg1.y; t1[2] = (bf16)areg1.z; t1[3] = (bf16)areg1.w;
            *(bf16x4*)&As[nxt][ar][ac * 4] = t0;
            *(bf16x4*)&As[nxt][ar + 32][ac * 4] = t1;
        }
        __syncthreads();
    }

    // epilogue: write bf16 q/k/v + sum of squares (fp32, pre-quantization)
    float sq = 0.f, sk = 0.f;
    #pragma unroll
    for (int mi = 0; mi < 4; mi++) {
        #pragma unroll
        for (int ni = 0; ni < 6; ni++) {
            int col = w * 96 + ni * 16 + lr;    // 16-wide frags never cross a 128 boundary
            int arr = col >> 7, cc = col & 127;
            bf16* dst = (arr == 0) ? qo : (arr == 1) ? ko : vo;
            #pragma unroll
            for (int r = 0; r < 4; r++) {
                int row = n0 + mi * 16 + lh * 4 + r;
                float val = acc[mi][ni][r];
                dst[(size_t)row * HD + cc] = (bf16)val;
                if (arr == 0) sq += val * val;
                else if (arr == 1) sk += val * val;
            }
        }
    }
    #pragma unroll
    for (int off = 32; off > 0; off >>= 1) {
        sq += __shfl_down(sq, off);
        sk += __shfl_down(sk, off);
    }
    if (lane == 0) { rq[w] = sq; rk[w] = sk; }
    __syncthreads();
    if (tid == 0) {
        float a = 0.f, b = 0.f;
        #pragma unroll
        for (int i = 0; i < 4; i++) { a += rq[i]; b += rk[i]; }
        atomicAdd(&sumsq[0], a);
        atomicAdd(&sumsq[1], b);
    }
}

// ---------------- K2: per-graph k^T v via MFMA (node-dim as K) ----------------
// grid 256 blocks (16 graphs x 16 chunks of 512 rows) x 512 threads (8 waves, 2x4).
__global__ __launch_bounds__(512, 1) void k2_kv(
    const bf16* __restrict__ ko, const bf16* __restrict__ vo,
    float* __restrict__ part_kv, float* __restrict__ part_ks)
{
    __shared__ __align__(16) char smem[16640];   // kt[32][130] | vt[32][130]; reused as f32 scr
    bf16 (*kt)[130] = (bf16(*)[130])smem;
    bf16 (*vt)[130] = (bf16(*)[130])(smem + 8320);
    float* scr = (float*)smem;

    const int tid = threadIdx.x, lane = tid & 63, w = tid >> 6;
    const int wr = w >> 2, wc = w & 3;           // 2 m-groups x 4 d-groups
    const int lr = lane & 15, lh = lane >> 4;
    const int b = blockIdx.x >> 4, cch = blockIdx.x & 15;
    const size_t l0 = (size_t)b * LMAX + (size_t)cch * 512;
    const int sr = tid >> 4, sc = tid & 15;      // staging row / col8

    f32x4 acc[4][2];
    #pragma unroll
    for (int mi = 0; mi < 4; mi++)
        #pragma unroll
        for (int ni = 0; ni < 2; ni++)
            acc[mi][ni] = (f32x4){0.f, 0.f, 0.f, 0.f};
    float ks8[8] = {};

    uint4 kk4 = *(const uint4*)&ko[(l0 + sr) * HD + sc * 8];
    uint4 vv4 = *(const uint4*)&vo[(l0 + sr) * HD + sc * 8];

    for (int lt = 0; lt < 512; lt += 32) {
        __syncthreads();   // prev compute done
        #pragma unroll
        for (int j2 = 0; j2 < 4; j2++) {
            *(unsigned int*)&kt[sr][sc * 8 + j2 * 2] = ((const unsigned int*)&kk4)[j2];
            *(unsigned int*)&vt[sr][sc * 8 + j2 * 2] = ((const unsigned int*)&vv4)[j2];
        }
        #pragma unroll
        for (int j = 0; j < 8; j++) ks8[j] += (float)((const bf16*)&kk4)[j];
        __syncthreads();   // tiles published
        if (lt + 32 < 512) {   // prefetch next tile during compute
            kk4 = *(const uint4*)&ko[(l0 + lt + 32 + sr) * HD + sc * 8];
            vv4 = *(const uint4*)&vo[(l0 + lt + 32 + sr) * HD + sc * 8];
        }
        bf16x8 a[4], bb[2];
        #pragma unroll
        for (int mi = 0; mi < 4; mi++) {
            int m = wr * 64 + mi * 16 + lr;
            #pragma unroll
            for (int j = 0; j < 8; j++) a[mi][j] = kt[lh * 8 + j][m];
        }
        #pragma unroll
        for (int ni = 0; ni < 2; ni++) {
            int d = wc * 32 + ni * 16 + lr;
            #pragma unroll
            for (int j = 0; j < 8; j++) bb[ni][j] = vt[lh * 8 + j][d];
        }
        #pragma unroll
        for (int mi = 0; mi < 4; mi++)
            #pragma unroll
            for (int ni = 0; ni < 2; ni++)
                acc[mi][ni] = __builtin_amdgcn_mfma_f32_16x16x32_bf16(
                    a[mi], bb[ni], acc[mi][ni], 0, 0, 0);
    }

    // ks partial: reduce per-thread col-sums across the 32 row-groups
    __syncthreads();
    #pragma unroll
    for (int j = 0; j < 8; j++) scr[tid * 8 + j] = ks8[j];
    __syncthreads();
    if (tid < 128) {
        float s = 0.f;
        #pragma unroll
        for (int g = 0; g < 32; g++)
            s += scr[((g << 4) | (tid >> 3)) * 8 + (tid & 7)];
        part_ks[blockIdx.x * HD + tid] = s;
    }

    float* dst = part_kv + (size_t)blockIdx.x * 16384;
    #pragma unroll
    for (int mi = 0; mi < 4; mi++)
        #pragma unroll
        for (int ni = 0; ni < 2; ni++)
            #pragma unroll
            for (int r = 0; r < 4; r++) {
                int m = wr * 64 + mi * 16 + lh * 4 + r;
                int d = wc * 32 + ni * 16 + lr;
                dst[m * HD + d] = acc[mi][ni][r];
            }
}

// ---------------- K2b: reduce 16 partials/graph, apply s_q*s_k, write kvs^T ----------------
__global__ __launch_bounds__(256, 1) void k2b_reduce(
    const float* __restrict__ part_kv, const float* __restrict__ part_ks,
    const float* __restrict__ sumsq,
    bf16* __restrict__ kvsT, float* __restrict__ ks_sum_s)
{
    const int b = blockIdx.x >> 3, ms = blockIdx.x & 7, tid = threadIdx.x;
    const float s_qk = rsqrtf(sumsq[0]) * rsqrtf(sumsq[1]);

    #pragma unroll
    for (int i = 0; i < 8; i++) {
        int idx = i * 256 + tid;               // 2048 outputs for this m-slice
        int m = ms * 16 + (idx >> 7), d = idx & 127;
        float s = 0.f;
        #pragma unroll
        for (int c = 0; c < 16; c++)
            s += part_kv[((size_t)(b * 16 + c) << 14) + (m << 7) + d];
        kvsT[((size_t)b << 14) + (d << 7) + m] = (bf16)(s * s_qk);
    }
    if (ms == 0 && tid < 128) {
        float s = 0.f;
        #pragma unroll
        for (int c = 0; c < 16; c++)
            s += part_ks[(b * 16 + c) * HD + tid];
        ks_sum_s[b * HD + tid] = s * s_qk;
    }
}

// ---------------- K3: out = (q @ kvsT + 16 v) / (q . ks_sum_s + 16) ----------------
// 70 KB LDS -> 2 blocks/CU; kvsT B-frags read direct from global (L2-hot, 32 KB/graph).
__global__ __launch_bounds__(256, 2) void k3_out(
    const bf16* __restrict__ qo, const bf16* __restrict__ vo,
    const bf16* __restrict__ kvsT, const float* __restrict__ ks_sum_s,
    float* __restrict__ out)
{
    __shared__ bf16 qs[128][136];
    __shared__ bf16 vsh[128][136];
    __shared__ float kss[128];
    __shared__ float denom[128];
    const int tid = threadIdx.x, lane = tid & 63, w = tid >> 6;
    const int lr = lane & 15, lh = lane >> 4;
    const int n0 = blockIdx.x * 128;
    const int b = n0 >> 13;

    #pragma unroll
    for (int i = 0; i < 8; i++) {
        int idx = tid + i * 256;
        int r = idx >> 4, c8 = idx & 15;
        *(bf16x8*)&qs[r][c8 * 8]  = *(const bf16x8*)&qo[(size_t)(n0 + r) * HD + c8 * 8];
        *(bf16x8*)&vsh[r][c8 * 8] = *(const bf16x8*)&vo[(size_t)(n0 + r) * HD + c8 * 8];
    }
    if (tid < 128) kss[tid] = ks_sum_s[b * HD + tid];
    __syncthreads();

    if (tid < 128) {
        float s = 0.f;
        #pragma unroll 8
        for (int m = 0; m < HD; m++) s += (float)qs[tid][m] * kss[m];
        denom[tid] = s + 16.0f;
    }

    f32x4 acc[2][8];
    #pragma unroll
    for (int mi = 0; mi < 2; mi++)
        #pragma unroll
        for (int ni = 0; ni < 8; ni++)
            acc[mi][ni] = (f32x4){0.f, 0.f, 0.f, 0.f};

    #pragma unroll
    for (int k0 = 0; k0 < HD; k0 += 32) {
        bf16x8 a[2], bb[8];
        #pragma unroll
        for (int mi = 0; mi < 2; mi++)
            a[mi] = *(const bf16x8*)&qs[w * 32 + mi * 16 + lr][k0 + lh * 8];
        #pragma unroll
        for (int ni = 0; ni < 8; ni++)
            bb[ni] = *(const bf16x8*)&kvsT[(size_t)b * 16384 + (size_t)(ni * 16 + lr) * HD + k0 + lh * 8];
        #pragma unroll
        for (int mi = 0; mi < 2; mi++)
            #pragma unroll
            for (int ni = 0; ni < 8; ni++)
                acc[mi][ni] = __builtin_amdgcn_mfma_f32_16x16x32_bf16(
                    a[mi], bb[ni], acc[mi][ni], 0, 0, 0);
    }
    __syncthreads();   // denom ready

    #pragma unroll
    for (int mi = 0; mi < 2; mi++) {
        #pragma unroll
        for (int ni = 0; ni < 8; ni++) {
            int col = ni * 16 + lr;
            #pragma unroll
            for (int r = 0; r < 4; r++) {
                int row = w * 32 + mi * 16 + lh * 4 + r;
                float vv = (float)vsh[row][col];
                out[(size_t)(n0 + row) * HD + col] =
                    (acc[mi][ni][r] + 16.0f * vv) / denom[row];
            }
        }
    }
}

// ---------------- launch ----------------
extern "C" void kernel_launch(void* const* d_in, const int* in_sizes, int n_in,
                              void* d_out, int out_size, void* d_ws, size_t ws_size,
                              hipStream_t stream)
{
    const float* x  = (const float*)d_in[0];
    const float* Wq = (const float*)d_in[1];
    const float* Wk = (const float*)d_in[2];
    const float* Wv = (const float*)d_in[3];

    char* ws = (char*)d_ws;
    const size_t Q_OFF   = 0;                       // 131072*128*2 = 33554432
    const size_t K_OFF   = 33554432;
    const size_t V_OFF   = 67108864;
    const size_t PKV_OFF = 100663296;               // 256*16384*4 = 16777216
    const size_t PKS_OFF = 117440512;               // 256*128*4   = 131072
    const size_t KVS_OFF = 117571584;               // 16*16384*2  = 524288
    const size_t KSS_OFF = 118095872;               // 16*128*4    = 8192
    const size_t SSQ_OFF = 118104064;               // 2*4
    const size_t NEED    = 118104072;
    if (ws_size < NEED) return;

    bf16*  qo      = (bf16*)(ws + Q_OFF);
    bf16*  ko      = (bf16*)(ws + K_OFF);
    bf16*  vo      = (bf16*)(ws + V_OFF);
    float* part_kv = (float*)(ws + PKV_OFF);
    float* part_ks = (float*)(ws + PKS_OFF);
    bf16*  kvsT    = (bf16*)(ws + KVS_OFF);
    float* ks_sum  = (float*)(ws + KSS_OFF);
    float* sumsq   = (float*)(ws + SSQ_OFF);
    // wsW (393216 B) overlaps part_kv region: live only k0->k1, dead before k2 writes part_kv
    bf16*  wsW     = (bf16*)(ws + PKV_OFF);

    hipMemsetAsync(sumsq, 0, 8, stream);
    k0_prep<<<dim3(96), dim3(256), 0, stream>>>(Wq, Wk, Wv, wsW);
    k1_proj<<<dim3(N_NODES / 64), dim3(256), 0, stream>>>(x, wsW, qo, ko, vo, sumsq);
    k2_kv<<<dim3(256), dim3(512), 0, stream>>>(ko, vo, part_kv, part_ks);
    k2b_reduce<<<dim3(128), dim3(256), 0, stream>>>(part_kv, part_ks, sumsq, kvsT, ks_sum);
    k3_out<<<dim3(N_NODES / 128), dim3(256), 0, stream>>>(qo, vo, kvsT, ks_sum, (float*)d_out);
}